// Round 17
// baseline (349.891 us; speedup 1.0000x reference)
//
#include <hip/hip_runtime.h>
#include <math.h>

#define G 64
#define NDIM 512
#define FIN 7
#define HID 64
#define CLS 2
#define KPOOL 128

typedef unsigned long long u64;

__device__ __forceinline__ float wred64(float v){
  #pragma unroll
  for (int o = 32; o > 0; o >>= 1) v += __shfl_xor(v, o, 64);
  return v;
}

// ---- build transposed bitmasks: maskT[g][u][i] bit l = adj[g][i][u*64+l] ---
__global__ __launch_bounds__(256) void mask_kernel(const float* __restrict__ adj,
                                                   u64* __restrict__ maskT){
  const int wid = threadIdx.x >> 6, lane = threadIdx.x & 63;
  const int row = blockIdx.x * 4 + wid;          // [0, G*NDIM)
  const int g = row >> 9, i = row & 511;
  const float* ar = adj + (size_t)row * NDIM;
  u64 b[8];
  #pragma unroll
  for (int u = 0; u < 8; u++)
    b[u] = __ballot(ar[u * 64 + lane] != 0.0f);
  if (lane == 0){
    u64* mt = maskT + (size_t)g * 8 * NDIM + i;
    #pragma unroll
    for (int u = 0; u < 8; u++) mt[(size_t)u * NDIM] = b[u];
  }
}

// 8-wide neighbor-sum walk over an LDS table with 9-float (36B) row stride:
// one address per neighbor, 8 offset-immediate b32 reads, 8 distinct banks.
#define WALK(SRC, DST) { \
  float a_[8] = {0,0,0,0,0,0,0,0}; \
  _Pragma("unroll") \
  for (int u_ = 0; u_ < 8; u_++){ \
    u64 mm_ = mk[u_]; \
    while (mm_){ \
      int l_ = __builtin_ctzll(mm_); mm_ &= mm_ - 1; \
      const float* p_ = (SRC) + (u_ * 64 + l_) * 9; \
      _Pragma("unroll") \
      for (int e_ = 0; e_ < 8; e_++) a_[e_] += p_[e_]; \
    } \
  } \
  _Pragma("unroll") \
  for (int e_ = 0; e_ < 8; e_++) (DST)[e_] = a_[e_]; \
}

// ---- giga: ONE block per graph (512 threads): d-chain, w-chain, fin, topk,
//      xp, pool, gcn, head — all block-local, LDS time-multiplexed (45 KB).
__global__ __launch_bounds__(512) void giga_kernel(
    const u64* __restrict__ maskT, const float* __restrict__ x,
    const float* __restrict__ panw, const float* __restrict__ w1,
    const float* __restrict__ b1, const float* __restrict__ pvec,
    const float* __restrict__ beta, const float* __restrict__ gw,
    const float* __restrict__ gb, const float* __restrict__ lw,
    const float* __restrict__ lb,
    float* __restrict__ xp, float* __restrict__ Apool,
    float* __restrict__ out)
{
  __shared__ __align__(16) char smem[46080];
  float* dl   = (float*)(smem);                    // [0,2048)      alive always
  float* sv   = (float*)(smem + 2048);             // [2048,4096)   scores
  int*   idxs = (int*)(smem + 4096);               // [4096,4608)   topk idx
  float* di_l = (float*)(smem + 4608);             // [4608,5120)   pooled di
  float* sA   = (float*)(smem + 5120);             // [5120,7168)   deg
  float* sB   = (float*)(smem + 7168);             // [7168,9216)   d2
  float* zA   = (float*)(smem + 9216);             // [9216,27648)  512x9 f
  float* zB   = (float*)(smem + 27648);            // [27648,46080) 512x9 f
  float* Wl   = (float*)(smem + 27648);            // 576 f (fin; zB dead)
  u64 (*mt)[NDIM] = (u64 (*)[NDIM])(smem + 5120);  // pool: 32KB [5120,37888)
  unsigned char (*arow)[NDIM] =
      (unsigned char (*)[NDIM])(smem + 37888);     // pool: 8KB [37888,46080)
  float* h2buf = (float*)(smem + 5120);            // gcn: 32KB (mt dead)

  const int g = blockIdx.x;
  const int t = threadIdx.x;                       // row (walk phases)
  const int w = t >> 6, lane = t & 63;

  // own-row masks + x in registers
  u64 mk[8];
  #pragma unroll
  for (int u = 0; u < 8; u++)
    mk[u] = maskT[(size_t)g * 8 * NDIM + (size_t)u * NDIM + t];
  float xr[FIN];
  #pragma unroll
  for (int f = 0; f < FIN; f++) xr[f] = x[((size_t)g * NDIM + t) * FIN + f];
  const float w0 = panw[0], ww1 = panw[1], ww2 = panw[2], ww3 = panw[3];
  const float c0 = w0, c1 = c0 * ww1, c2 = c1 * ww2, c3 = c2 * ww3;

  // P1: deg
  float dg = 0.f;
  #pragma unroll
  for (int u = 0; u < 8; u++) dg += (float)__popcll(mk[u]);
  sA[t] = dg;
  __syncthreads();
  // P2: d2 = A.deg
  float d2 = 0.f;
  #pragma unroll
  for (int u = 0; u < 8; u++){
    u64 mm = mk[u];
    while (mm){ int l = __builtin_ctzll(mm); mm &= mm - 1; d2 += sA[u * 64 + l]; }
  }
  sB[t] = d2;
  __syncthreads();
  // P3: d3 = A.d2 ; dd ; z = [dd, dd*x]
  float d3 = 0.f;
  #pragma unroll
  for (int u = 0; u < 8; u++){
    u64 mm = mk[u];
    while (mm){ int l = __builtin_ctzll(mm); mm &= mm - 1; d3 += sB[u * 64 + l]; }
  }
  const float dd = rsqrtf(fmaxf(c0 + c1 * dg + c2 * d2 + c3 * d3, 1.0f));
  dl[t] = dd;
  zA[t * 9 + 0] = dd;
  #pragma unroll
  for (int f = 0; f < FIN; f++) zA[t * 9 + 1 + f] = dd * xr[f];
  __syncthreads();
  // P4: w1 = A.z
  float aw1[8], aw2[8], aw3[8];
  WALK(zA, aw1);
  #pragma unroll
  for (int e = 0; e < 8; e++) zB[t * 9 + e] = aw1[e];
  __syncthreads();
  // P5: w2 = A.w1 (write into zA; z dead, no one reads zA this phase)
  WALK(zB, aw2);
  #pragma unroll
  for (int e = 0; e < 8; e++) zA[t * 9 + e] = aw2[e];
  __syncthreads();
  // P6: w3 = A.w2 (registers only) + stage weights into freed zB region
  WALK(zA, aw3);
  for (int q = t; q < FIN * HID; q += 512) Wl[q] = w1[q];
  if (t < HID){ Wl[448 + t] = pvec[t]; Wl[512 + t] = b1[t]; }
  __syncthreads();
  // P7: fin — s2, yin, h(on the fly), s1, score
  const float s2v = dd * (c0 * dd + c1 * aw1[0] + c2 * aw2[0] + c3 * aw3[0]);
  float yin[FIN];
  #pragma unroll
  for (int f = 0; f < FIN; f++){
    float zv = dd * xr[f];
    float y = c0 * zv;
    y += c1 * aw1[f + 1];
    y += c2 * aw2[f + 1];
    y += c3 * aw3[f + 1];
    yin[f] = dd * y;
  }
  float s1 = 0.f;
  #pragma unroll
  for (int o = 0; o < HID; o++){
    float zz = Wl[512 + o];
    #pragma unroll
    for (int f = 0; f < FIN; f++) zz = fmaf(yin[f], Wl[f * HID + o], zz);
    s1 = fmaf(fmaxf(zz, 0.f), Wl[448 + o], s1);
  }
  const float sc = tanhf(beta[0] * s1 + beta[1] * s2v);
  sv[t] = sc;
  __syncthreads();
  // P8: rank-select topk + xp scatter (recompute h for selected rows)
  {
    int rank = 0;
    #pragma unroll 8
    for (int j = 0; j < NDIM; j++){
      float u_ = sv[j];
      rank += (u_ > sc || (u_ == sc && j < t)) ? 1 : 0;
    }
    if (rank < KPOOL){
      idxs[rank] = t;
      float* xrow = xp + ((size_t)g * KPOOL + rank) * HID;
      for (int o = 0; o < HID; o++){
        float zz = Wl[512 + o];
        #pragma unroll
        for (int f = 0; f < FIN; f++) zz = fmaf(yin[f], Wl[f * HID + o], zz);
        xrow[o] = fmaxf(zz, 0.f) * sc;
      }
    }
  }
  __syncthreads();
  // P9: masks -> LDS table (mt overlays sA/sB/zA/Wl — all dead)
  #pragma unroll
  for (int u = 0; u < 8; u++) mt[u][t] = mk[u];
  __syncthreads();
  // P10: pool — Apool = Mn[idx,idx] + I (global), di_l (LDS)
  {
    float* Apg = Apool + (size_t)g * KPOOL * KPOOL;
    const int c0i = lane * 2, c1i = lane * 2 + 1;
    const int ic0 = idxs[c0i], ic1 = idxs[c1i];
    u64 cm0[8], cm1[8];
    #pragma unroll
    for (int u = 0; u < 8; u++){ cm0[u] = mt[u][ic0]; cm1[u] = mt[u][ic1]; }
    const float dc0 = dl[ic0], dc1 = dl[ic1];
    #pragma unroll 1
    for (int rg = 0; rg < 8; rg++){
      #pragma unroll
      for (int e = 0; e < 2; e++){
        const int j = w * 2 + e;
        const int ir = idxs[rg * 16 + j];
        u64 rm[8];
        #pragma unroll
        for (int u = 0; u < 8; u++) rm[u] = mt[u][ir];
        #pragma unroll
        for (int q = 0; q < 8; q++){
          int c = 0;
          #pragma unroll
          for (int u = 0; u < 8; u++)
            c += (int)__popcll(mt[u][q * 64 + lane] & rm[u]);
          arow[j][q * 64 + lane] = (unsigned char)c;
        }
      }
      __syncthreads();
      #pragma unroll
      for (int e = 0; e < 2; e++){
        const int j = w * 2 + e;
        const int r = rg * 16 + j;
        const int ir = idxs[r];
        const float dpr = dl[ir];
        const unsigned char* aj = arow[j];
        float a30 = 0.f, a31 = 0.f;
        #pragma unroll
        for (int u = 0; u < 8; u++){
          u64 m0 = cm0[u];
          while (m0){ int l = __builtin_ctzll(m0); m0 &= m0 - 1; a30 += (float)aj[u * 64 + l]; }
          u64 m1 = cm1[u];
          while (m1){ int l = __builtin_ctzll(m1); m1 &= m1 - 1; a31 += (float)aj[u * 64 + l]; }
        }
        float ab0 = (float)((cm0[ir >> 6] >> (ir & 63)) & 1ull);
        float ab1 = (float)((cm1[ir >> 6] >> (ir & 63)) & 1ull);
        float m0 = fmaf(c3, a30, fmaf(c2, (float)aj[ic0], c1 * ab0));
        float m1 = fmaf(c3, a31, fmaf(c2, (float)aj[ic1], c1 * ab1));
        if (r == c0i) m0 += c0;
        if (r == c1i) m1 += c0;
        float v0 = m0 * dpr * dc0;
        float v1 = m1 * dpr * dc1;
        if (r == c0i) v0 += 1.0f;
        if (r == c1i) v1 += 1.0f;
        *(float2*)&Apg[(size_t)r * KPOOL + c0i] = make_float2(v0, v1);
        float s = wred64(v0 + v1);
        if (lane == 0) di_l[r] = s > 0.f ? rsqrtf(s) : 0.f;
      }
      __syncthreads();
    }
  }
  __syncthreads();
  // P11: gcn — h2 = relu((An xp) gw + gb) into h2buf (mt dead)
  {
    const float* Apg = Apool + (size_t)g * KPOOL * KPOOL;
    const float* xpg = xp + (size_t)g * KPOOL * HID;
    #pragma unroll 1
    for (int it = 0; it < 16; it++){
      const int r = it * 8 + w;
      const float dir = di_l[r];
      float acc = 0.f;
      for (int b = 0; b < KPOOL; b++){
        float an = Apg[(size_t)r * KPOOL + b] * dir * di_l[b];
        acc = fmaf(an, xpg[b * HID + lane], acc);
      }
      float zz = gb[lane];
      for (int f = 0; f < HID; f++)
        zz = fmaf(__shfl(acc, f, 64), gw[f * HID + lane], zz);
      h2buf[r * HID + lane] = fmaxf(zz, 0.f);
    }
  }
  __syncthreads();
  // P12: head — pooled sum + linear + log_softmax (wave 0)
  if (t < HID){
    float p = 0.f;
    for (int k = 0; k < KPOOL; k++) p += h2buf[k * HID + t];
    float z0 = p * lw[t * CLS + 0];
    float z1 = p * lw[t * CLS + 1];
    z0 = wred64(z0);
    z1 = wred64(z1);
    if (t == 0){
      float l0 = z0 + lb[0], l1 = z1 + lb[1];
      float m = fmaxf(l0, l1);
      float lse = m + logf(expf(l0 - m) + expf(l1 - m));
      out[g * CLS + 0] = l0 - lse;
      out[g * CLS + 1] = l1 - lse;
    }
  }
}

extern "C" void kernel_launch(void* const* d_in, const int* in_sizes, int n_in,
                              void* d_out, int out_size, void* d_ws, size_t ws_size,
                              hipStream_t stream)
{
  const float* x    = (const float*)d_in[0];
  const float* adj  = (const float*)d_in[1];
  const float* panw = (const float*)d_in[2];
  const float* w1   = (const float*)d_in[3];
  const float* b1   = (const float*)d_in[4];
  const float* pvec = (const float*)d_in[5];
  const float* beta = (const float*)d_in[6];
  const float* gw   = (const float*)d_in[7];
  const float* gbv  = (const float*)d_in[8];
  const float* lw   = (const float*)d_in[9];
  const float* lb   = (const float*)d_in[10];
  float* out = (float*)d_out;

  char* ws = (char*)d_ws;
  u64*   maskT = (u64*)ws;                                  // 2 MB
  float* xp    = (float*)(ws + (1 << 21));                  // 2 MB
  float* Apool = (float*)(ws + (1 << 21) + (1 << 21));      // 4 MB

  mask_kernel<<<G * NDIM / 4, 256, 0, stream>>>(adj, maskT);
  giga_kernel<<<G, 512, 0, stream>>>(maskT, x, panw, w1, b1, pvec, beta,
                                     gw, gbv, lw, lb, xp, Apool, out);
}

// Round 18
// 179.426 us; speedup vs baseline: 1.9501x; 1.9501x over previous
//
#include <hip/hip_runtime.h>
#include <math.h>

#define G 64
#define NDIM 512
#define FIN 7
#define HID 64
#define CLS 2
#define KPOOL 128

typedef unsigned long long u64;

__device__ __forceinline__ float wred64(float v){
  #pragma unroll
  for (int o = 32; o > 0; o >>= 1) v += __shfl_xor(v, o, 64);
  return v;
}

// XCD-aware decode for 512-block per-graph-chunk kernels
#define XCD_DECODE(bid, g, chunk) \
  const int g = ((bid) & 7) + 8 * (((bid) >> 3) & 7); \
  const int chunk = (bid) >> 6;

// ---- build transposed bitmasks: maskT[g][u][i] bit l = adj[g][i][u*64+l] ---
__global__ __launch_bounds__(256) void mask_kernel(const float* __restrict__ adj,
                                                   u64* __restrict__ maskT){
  const int wid = threadIdx.x >> 6, lane = threadIdx.x & 63;
  const int row = blockIdx.x * 4 + wid;          // [0, G*NDIM)
  const int g = row >> 9, i = row & 511;
  const float* ar = adj + (size_t)row * NDIM;
  u64 b[8];
  #pragma unroll
  for (int u = 0; u < 8; u++)
    b[u] = __ballot(ar[u * 64 + lane] != 0.0f);
  if (lane == 0){
    u64* mt = maskT + (size_t)g * 8 * NDIM + i;
    #pragma unroll
    for (int u = 0; u < 8; u++) mt[(size_t)u * NDIM] = b[u];
  }
}

// ---- mega v2: per-block (g, 64-row chunk): deg/d2/d3/dd, z, w1, w2 for ALL
//      512 rows (redundant, no grid deps); w3 + h + score for OWN 64 rows.
//      z/w tables: 9-float (36B) row stride -> row k starts at bank (9k)%32,
//      9 coprime 32 => all banks cycled; 1 addr + 8 offset-imm reads/neighbor
//      (giga r17 measured: 1.0M conflicts vs stride-8 AoS 6.4M).
//      Own-row masks in REGISTERS; no 32KB LDS mask table. LDS = 43.3 KB.
__global__ __launch_bounds__(256) void mega_kernel(
    const u64* __restrict__ maskT, const float* __restrict__ x,
    const float* __restrict__ panw, const float* __restrict__ w1,
    const float* __restrict__ b1, const float* __restrict__ pvec,
    const float* __restrict__ beta,
    float* __restrict__ dvec, float* __restrict__ score,
    float* __restrict__ hbuf)
{
  __shared__ float deg_s[NDIM];                    // 2 KB
  __shared__ float d2_s[NDIM];                     // 2 KB
  __shared__ __align__(16) float zA[NDIM * 9];     // 18 KB
  __shared__ __align__(16) float zB[NDIM * 9];     // 18 KB
  __shared__ float Wl[576];                        // 2.3 KB

  const int bid = blockIdx.x;
  XCD_DECODE(bid, g, chunk)
  const int tid = threadIdx.x;
  const int r0 = tid, r1 = tid + 256;
  const bool own0 = (r0 >> 6) == chunk, own1 = (r1 >> 6) == chunk;

  // own-row masks -> registers (coalesced global loads; maskT is L2-resident)
  u64 mk0[8], mk1[8];
  #pragma unroll
  for (int u = 0; u < 8; u++){
    const u64* mu = maskT + (size_t)g * 8 * NDIM + (size_t)u * NDIM;
    mk0[u] = mu[r0];
    mk1[u] = mu[r1];
  }
  const float w0 = panw[0], ww1 = panw[1], ww2 = panw[2], ww3 = panw[3];
  const float c0 = w0, c1 = c0 * ww1, c2 = c1 * ww2, c3 = c2 * ww3;

  // deg for all rows
  float dg0 = 0.f, dg1 = 0.f;
  #pragma unroll
  for (int u = 0; u < 8; u++){
    dg0 += (float)__popcll(mk0[u]);
    dg1 += (float)__popcll(mk1[u]);
  }
  deg_s[r0] = dg0; deg_s[r1] = dg1;
  __syncthreads();
  // d2 = A . deg
  float d20 = 0.f, d21 = 0.f;
  #pragma unroll
  for (int u = 0; u < 8; u++){
    u64 m0 = mk0[u];
    while (m0){ int l = __builtin_ctzll(m0); m0 &= m0 - 1; d20 += deg_s[u * 64 + l]; }
    u64 m1 = mk1[u];
    while (m1){ int l = __builtin_ctzll(m1); m1 &= m1 - 1; d21 += deg_s[u * 64 + l]; }
  }
  d2_s[r0] = d20; d2_s[r1] = d21;
  __syncthreads();
  // d3 = A . d2 ; dd = rsqrt(max(rowsum(M),1))
  float d30 = 0.f, d31 = 0.f;
  #pragma unroll
  for (int u = 0; u < 8; u++){
    u64 m0 = mk0[u];
    while (m0){ int l = __builtin_ctzll(m0); m0 &= m0 - 1; d30 += d2_s[u * 64 + l]; }
    u64 m1 = mk1[u];
    while (m1){ int l = __builtin_ctzll(m1); m1 &= m1 - 1; d31 += d2_s[u * 64 + l]; }
  }
  const float dd0 = rsqrtf(fmaxf(c0 + c1 * dg0 + c2 * d20 + c3 * d30, 1.0f));
  const float dd1 = rsqrtf(fmaxf(c0 + c1 * dg1 + c2 * d21 + c3 * d31, 1.0f));
  // z = [dd, dd*x]  (stride-9 AoS)
  float xr0[FIN], xr1[FIN];
  {
    const float* px0 = x + ((size_t)g * NDIM + r0) * FIN;
    const float* px1 = x + ((size_t)g * NDIM + r1) * FIN;
    #pragma unroll
    for (int f = 0; f < FIN; f++){ xr0[f] = px0[f]; xr1[f] = px1[f]; }
    zA[r0 * 9 + 0] = dd0; zA[r1 * 9 + 0] = dd1;
    #pragma unroll
    for (int f = 0; f < FIN; f++){
      zA[r0 * 9 + 1 + f] = dd0 * xr0[f];
      zA[r1 * 9 + 1 + f] = dd1 * xr1[f];
    }
    if (own0) dvec[g * NDIM + r0] = dd0;
    if (own1) dvec[g * NDIM + r1] = dd1;
  }
  __syncthreads();
  float aw1[8], aw2[8], aw3[8];
  // w1 = A . z  (zB <- walk zA)
  {
    float a0[8] = {0,0,0,0,0,0,0,0}, a1[8] = {0,0,0,0,0,0,0,0};
    #pragma unroll
    for (int u = 0; u < 8; u++){
      u64 m0 = mk0[u];
      while (m0){
        int l = __builtin_ctzll(m0); m0 &= m0 - 1;
        const float* p = zA + (u * 64 + l) * 9;
        #pragma unroll
        for (int e = 0; e < 8; e++) a0[e] += p[e];
      }
      u64 m1 = mk1[u];
      while (m1){
        int l = __builtin_ctzll(m1); m1 &= m1 - 1;
        const float* p = zA + (u * 64 + l) * 9;
        #pragma unroll
        for (int e = 0; e < 8; e++) a1[e] += p[e];
      }
    }
    #pragma unroll
    for (int e = 0; e < 8; e++){ zB[r0 * 9 + e] = a0[e]; zB[r1 * 9 + e] = a1[e]; }
    #pragma unroll
    for (int e = 0; e < 8; e++) aw1[e] = own0 ? a0[e] : a1[e];
  }
  __syncthreads();
  // w2 = A . w1  (zA <- walk zB)
  {
    float a0[8] = {0,0,0,0,0,0,0,0}, a1[8] = {0,0,0,0,0,0,0,0};
    #pragma unroll
    for (int u = 0; u < 8; u++){
      u64 m0 = mk0[u];
      while (m0){
        int l = __builtin_ctzll(m0); m0 &= m0 - 1;
        const float* p = zB + (u * 64 + l) * 9;
        #pragma unroll
        for (int e = 0; e < 8; e++) a0[e] += p[e];
      }
      u64 m1 = mk1[u];
      while (m1){
        int l = __builtin_ctzll(m1); m1 &= m1 - 1;
        const float* p = zB + (u * 64 + l) * 9;
        #pragma unroll
        for (int e = 0; e < 8; e++) a1[e] += p[e];
      }
    }
    __syncthreads();                   // all zB reads done before zA overwrite
    #pragma unroll
    for (int e = 0; e < 8; e++){ zA[r0 * 9 + e] = a0[e]; zA[r1 * 9 + e] = a1[e]; }
    #pragma unroll
    for (int e = 0; e < 8; e++) aw2[e] = own0 ? a0[e] : a1[e];
  }
  // stage weights — strided (256 threads, 448 elems)
  for (int q = tid; q < FIN * HID; q += 256) Wl[q] = w1[q];
  if (tid < HID){ Wl[448 + tid] = pvec[tid]; Wl[512 + tid] = b1[tid]; }
  __syncthreads();
  // w3 for OWN rows only + finalize
  if (own0 | own1){
    const int ro = own0 ? r0 : r1;
    const float dd = own0 ? dd0 : dd1;
    const int row = g * NDIM + ro;
    #pragma unroll
    for (int e = 0; e < 8; e++) aw3[e] = 0.f;
    #pragma unroll
    for (int u = 0; u < 8; u++){
      u64 mm = own0 ? mk0[u] : mk1[u];
      while (mm){
        int l = __builtin_ctzll(mm); mm &= mm - 1;
        const float* p = zA + (u * 64 + l) * 9;
        #pragma unroll
        for (int e = 0; e < 8; e++) aw3[e] += p[e];
      }
    }
    const float s2v = dd * (c0 * dd + c1 * aw1[0] + c2 * aw2[0] + c3 * aw3[0]);
    float yin[FIN];
    #pragma unroll
    for (int f = 0; f < FIN; f++){
      float zv = dd * (own0 ? xr0[f] : xr1[f]);
      float y = c0 * zv;
      y += c1 * aw1[f + 1];
      y += c2 * aw2[f + 1];
      y += c3 * aw3[f + 1];
      yin[f] = dd * y;
    }
    float hv[HID];
    float s1 = 0.f;
    #pragma unroll
    for (int o = 0; o < HID; o++){
      float zz = Wl[512 + o];
      #pragma unroll
      for (int f = 0; f < FIN; f++) zz = fmaf(yin[f], Wl[f * HID + o], zz);
      hv[o] = fmaxf(zz, 0.f);
      s1 = fmaf(hv[o], Wl[448 + o], s1);
    }
    score[row] = tanhf(beta[0] * s1 + beta[1] * s2v);
    float* hr = hbuf + (size_t)row * HID;
    #pragma unroll
    for (int o = 0; o < HID; o++) hr[o] = hv[o];
  }
}

// ---- top-k rank selection + xp gather -------------------------------------
__global__ __launch_bounds__(512) void topk_kernel(const float* __restrict__ score,
                                                   const float* __restrict__ hbuf,
                                                   int* __restrict__ idxOut,
                                                   float* __restrict__ xp)
{
  const int g = blockIdx.x, t = threadIdx.x;        // 512
  __shared__ float sv[NDIM];
  sv[t] = score[g * NDIM + t];
  __syncthreads();
  const float v = sv[t];
  int rank = 0;
  #pragma unroll 8
  for (int j = 0; j < NDIM; j++){
    float u_ = sv[j];
    rank += (u_ > v || (u_ == v && j < t)) ? 1 : 0;
  }
  if (rank < KPOOL){
    idxOut[g * KPOOL + rank] = t;
    const float* hr = hbuf + ((size_t)g * NDIM + t) * HID;
    float* xr = xp + ((size_t)g * KPOOL + rank) * HID;
    #pragma unroll
    for (int o = 0; o < HID; o++) xr[o] = hr[o] * v;
  }
}

// ---- pooled adjacency (fused A2p): Apool = Mn[idx,idx] + I, di ------------
__global__ __launch_bounds__(512) void pool_kernel(
    const u64* __restrict__ maskT, const int* __restrict__ idx,
    const float* __restrict__ dvec, const float* __restrict__ panw,
    float* __restrict__ Apool, float* __restrict__ di)
{
  const int b = blockIdx.x;
  const int g = b >> 3, rowgrp = b & 7;
  const int tid = threadIdx.x, w = tid >> 6, lane = tid & 63;
  __shared__ u64 mt[8][NDIM];                    // 32 KB
  __shared__ unsigned char arow[16][NDIM];       // 8 KB
  __shared__ int idxs[KPOOL];
  __shared__ float dp[KPOOL];
  {
    const uint4* s4 = (const uint4*)(maskT + (size_t)g * 8 * NDIM);
    uint4* d4 = (uint4*)&mt[0][0];
    #pragma unroll
    for (int s = 0; s < 4; s++) d4[tid + 512 * s] = s4[tid + 512 * s];
  }
  if (tid < KPOOL){
    int ia = idx[g * KPOOL + tid];
    idxs[tid] = ia;
    dp[tid] = dvec[g * NDIM + ia];
  }
  __syncthreads();
  // compute the 16 pooled A2 rows in-block (register-tiled popcounts)
  #pragma unroll
  for (int e = 0; e < 2; e++){
    const int j = w * 2 + e;
    const int ir = idxs[rowgrp * 16 + j];
    u64 rm[8];
    #pragma unroll
    for (int u = 0; u < 8; u++) rm[u] = mt[u][ir];   // wave-uniform broadcast
    #pragma unroll
    for (int q = 0; q < 8; q++){
      int c = 0;
      #pragma unroll
      for (int u = 0; u < 8; u++)
        c += (int)__popcll(mt[u][q * 64 + lane] & rm[u]);
      arow[j][q * 64 + lane] = (unsigned char)c;
    }
  }
  const int c0i = lane * 2, c1i = lane * 2 + 1;
  const int ic0 = idxs[c0i], ic1 = idxs[c1i];
  u64 cm0[8], cm1[8];
  #pragma unroll
  for (int u = 0; u < 8; u++){
    cm0[u] = mt[u][ic0];
    cm1[u] = mt[u][ic1];
  }
  __syncthreads();
  const float w0 = panw[0], ww1 = panw[1], ww2 = panw[2], ww3 = panw[3];
  const float cc0 = w0, cc1 = cc0 * ww1, cc2 = cc1 * ww2, cc3 = cc2 * ww3;
  const float dc0 = dp[c0i], dc1 = dp[c1i];
  #pragma unroll
  for (int e = 0; e < 2; e++){
    const int j = w * 2 + e;
    const int r = rowgrp * 16 + j;
    const int ir = idxs[r];
    const float dpr = dp[r];
    const unsigned char* aj = arow[j];
    float a30 = 0.f, a31 = 0.f;
    #pragma unroll
    for (int u = 0; u < 8; u++){
      u64 m0 = cm0[u];
      while (m0){ int l = __builtin_ctzll(m0); m0 &= m0 - 1; a30 += (float)aj[u * 64 + l]; }
      u64 m1 = cm1[u];
      while (m1){ int l = __builtin_ctzll(m1); m1 &= m1 - 1; a31 += (float)aj[u * 64 + l]; }
    }
    float ab0 = (float)((cm0[ir >> 6] >> (ir & 63)) & 1ull);
    float ab1 = (float)((cm1[ir >> 6] >> (ir & 63)) & 1ull);
    float m0 = fmaf(cc3, a30, fmaf(cc2, (float)aj[ic0], cc1 * ab0));
    float m1 = fmaf(cc3, a31, fmaf(cc2, (float)aj[ic1], cc1 * ab1));
    if (r == c0i) m0 += cc0;
    if (r == c1i) m1 += cc0;
    float v0 = m0 * dpr * dc0;
    float v1 = m1 * dpr * dc1;
    if (r == c0i) v0 += 1.0f;
    if (r == c1i) v1 += 1.0f;
    float2 vv = make_float2(v0, v1);
    *(float2*)&Apool[((size_t)g * KPOOL + r) * KPOOL + c0i] = vv;
    float s = wred64(v0 + v1);
    if (lane == 0) di[g * KPOOL + r] = s > 0.f ? rsqrtf(s) : 0.f;
  }
}

// ---------------- pooled GCN: h2 = relu((An xp) W + b) ---------------------
__global__ __launch_bounds__(256) void gcn_kernel(
    const float* __restrict__ Apool, const float* __restrict__ di,
    const float* __restrict__ xp, const float* __restrict__ gw,
    const float* __restrict__ gb, float* __restrict__ h2)
{
  const int wid = threadIdx.x >> 6, lane = threadIdx.x & 63;
  const int row = blockIdx.x * 4 + wid;
  const int g = row >> 7, r = row & 127;
  const float dir = di[g * KPOOL + r];
  float acc = 0.f;
  for (int b = 0; b < KPOOL; b++){
    float an = Apool[(size_t)row * KPOOL + b] * dir * di[g * KPOOL + b];
    acc = fmaf(an, xp[((size_t)g * KPOOL + b) * HID + lane], acc);
  }
  __shared__ float ts[4][HID];
  ts[wid][lane] = acc;
  __syncthreads();
  float z = gb[lane];
  for (int f = 0; f < HID; f++) z = fmaf(ts[wid][f], gw[f * HID + lane], z);
  h2[(size_t)row * HID + lane] = fmaxf(z, 0.f);
}

// ---------------- head: pooled sum + linear + log_softmax ------------------
__global__ void head_kernel(const float* __restrict__ h2,
                            const float* __restrict__ lw,
                            const float* __restrict__ lb,
                            float* __restrict__ out)
{
  const int g = blockIdx.x;
  const int lane = threadIdx.x;
  float p = 0.f;
  for (int k = 0; k < KPOOL; k++) p += h2[((size_t)g * KPOOL + k) * HID + lane];
  float z0 = p * lw[lane * CLS + 0];
  float z1 = p * lw[lane * CLS + 1];
  z0 = wred64(z0);
  z1 = wred64(z1);
  if (lane == 0){
    float l0 = z0 + lb[0], l1 = z1 + lb[1];
    float m = fmaxf(l0, l1);
    float lse = m + logf(expf(l0 - m) + expf(l1 - m));
    out[g * CLS + 0] = l0 - lse;
    out[g * CLS + 1] = l1 - lse;
  }
}

extern "C" void kernel_launch(void* const* d_in, const int* in_sizes, int n_in,
                              void* d_out, int out_size, void* d_ws, size_t ws_size,
                              hipStream_t stream)
{
  const float* x    = (const float*)d_in[0];
  const float* adj  = (const float*)d_in[1];
  const float* panw = (const float*)d_in[2];
  const float* w1   = (const float*)d_in[3];
  const float* b1   = (const float*)d_in[4];
  const float* pvec = (const float*)d_in[5];
  const float* beta = (const float*)d_in[6];
  const float* gw   = (const float*)d_in[7];
  const float* gbv  = (const float*)d_in[8];
  const float* lw   = (const float*)d_in[9];
  const float* lb   = (const float*)d_in[10];
  float* out = (float*)d_out;

  char* ws = (char*)d_ws;
  const size_t NR = (size_t)G * NDIM;            // 32768 rows
  u64* maskT = (u64*)ws;                         // 2 MB
  char* p = ws + (1 << 21);
  float* dvec  = (float*)p;  p += NR * 4;
  float* score = (float*)p;  p += NR * 4;
  float* hbuf  = (float*)p;  p += NR * HID * 4;  // 8 MB
  int*   idx   = (int*)p;    p += (size_t)G * KPOOL * 4;
  float* xp    = (float*)p;  p += (size_t)G * KPOOL * HID * 4;
  float* Apool = (float*)p;  p += (size_t)G * KPOOL * KPOOL * 4;
  float* di    = (float*)p;  p += (size_t)G * KPOOL * 4;
  float* h2    = (float*)p;

  mask_kernel<<<G * NDIM / 4, 256, 0, stream>>>(adj, maskT);
  mega_kernel<<<512, 256, 0, stream>>>(maskT, x, panw, w1, b1, pvec, beta,
                                       dvec, score, hbuf);
  topk_kernel<<<G, 512, 0, stream>>>(score, hbuf, idx, xp);
  pool_kernel<<<G * 8, 512, 0, stream>>>(maskT, idx, dvec, panw, Apool, di);
  gcn_kernel<<<G * KPOOL / 4, 256, 0, stream>>>(Apool, di, xp, gw, gbv, h2);
  head_kernel<<<G, 64, 0, stream>>>(h2, lw, lb, out);
}

// Round 19
// 157.765 us; speedup vs baseline: 2.2178x; 1.1373x over previous
//
#include <hip/hip_runtime.h>
#include <math.h>

#define G 64
#define NDIM 512
#define FIN 7
#define HID 64
#define CLS 2
#define KPOOL 128

typedef unsigned long long u64;

__device__ __forceinline__ float wred64(float v){
  #pragma unroll
  for (int o = 32; o > 0; o >>= 1) v += __shfl_xor(v, o, 64);
  return v;
}

// ---- build transposed bitmasks: maskT[g][u][i] bit l = adj[g][i][u*64+l] ---
__global__ __launch_bounds__(256) void mask_kernel(const float* __restrict__ adj,
                                                   u64* __restrict__ maskT){
  const int wid = threadIdx.x >> 6, lane = threadIdx.x & 63;
  const int row = blockIdx.x * 4 + wid;          // [0, G*NDIM)
  const int g = row >> 9, i = row & 511;
  const float* ar = adj + (size_t)row * NDIM;
  u64 b[8];
  #pragma unroll
  for (int u = 0; u < 8; u++)
    b[u] = __ballot(ar[u * 64 + lane] != 0.0f);
  if (lane == 0){
    u64* mt = maskT + (size_t)g * 8 * NDIM + i;
    #pragma unroll
    for (int u = 0; u < 8; u++) mt[(size_t)u * NDIM] = b[u];
  }
}

// ---- mega v3: B=4 blocks/graph (was 8), 512 threads, 1 row/thread.
//      Redundant walk work per graph: 8704 -> 4608 rows (1.9x less).
//      deg/d2/d3/dd, z, w1, w2 for ALL 512 rows; w3 + h + score for
//      OWN 128 rows. Stride-9 z tables (r17-measured best). LDS 43.5 KB.
__global__ __launch_bounds__(512) void mega_kernel(
    const u64* __restrict__ maskT, const float* __restrict__ x,
    const float* __restrict__ panw, const float* __restrict__ w1,
    const float* __restrict__ b1, const float* __restrict__ pvec,
    const float* __restrict__ beta,
    float* __restrict__ dvec, float* __restrict__ score,
    float* __restrict__ hbuf)
{
  __shared__ float deg_s[NDIM];                    // 2 KB
  __shared__ float d2_s[NDIM];                     // 2 KB
  __shared__ __align__(16) float zA[NDIM * 9];     // 18 KB
  __shared__ __align__(16) float zB[NDIM * 9];     // 18 KB
  __shared__ float Wl[576];                        // 2.3 KB

  const int bid = blockIdx.x;                      // [0,256)
  const int g = (bid & 7) + 8 * ((bid >> 3) & 7);  // graph -> XCD bid%8
  const int chunk = bid >> 6;                      // [0,4): own rows [128c,+128)
  const int t = threadIdx.x;                       // row [0,512)

  // own-row masks -> registers (coalesced; maskT L2-resident)
  u64 mk[8];
  #pragma unroll
  for (int u = 0; u < 8; u++)
    mk[u] = maskT[(size_t)g * 8 * NDIM + (size_t)u * NDIM + t];
  float xr[FIN];
  {
    const float* px = x + ((size_t)g * NDIM + t) * FIN;
    #pragma unroll
    for (int f = 0; f < FIN; f++) xr[f] = px[f];
  }
  const float w0 = panw[0], ww1 = panw[1], ww2 = panw[2], ww3 = panw[3];
  const float c0 = w0, c1 = c0 * ww1, c2 = c1 * ww2, c3 = c2 * ww3;
  const bool own = (t >> 7) == chunk;

  // deg
  float dg = 0.f;
  #pragma unroll
  for (int u = 0; u < 8; u++) dg += (float)__popcll(mk[u]);
  deg_s[t] = dg;
  __syncthreads();
  // d2 = A . deg
  float d2 = 0.f;
  #pragma unroll
  for (int u = 0; u < 8; u++){
    u64 mm = mk[u];
    while (mm){ int l = __builtin_ctzll(mm); mm &= mm - 1; d2 += deg_s[u * 64 + l]; }
  }
  d2_s[t] = d2;
  __syncthreads();
  // d3 = A . d2 ; dd
  float d3 = 0.f;
  #pragma unroll
  for (int u = 0; u < 8; u++){
    u64 mm = mk[u];
    while (mm){ int l = __builtin_ctzll(mm); mm &= mm - 1; d3 += d2_s[u * 64 + l]; }
  }
  const float dd = rsqrtf(fmaxf(c0 + c1 * dg + c2 * d2 + c3 * d3, 1.0f));
  if (own) dvec[g * NDIM + t] = dd;
  // z = [dd, dd*x]  (stride-9 AoS)
  zA[t * 9 + 0] = dd;
  #pragma unroll
  for (int f = 0; f < FIN; f++) zA[t * 9 + 1 + f] = dd * xr[f];
  __syncthreads();
  // w1 = A . z
  float aw1[8], aw2[8], aw3[8];
  {
    float a[8] = {0,0,0,0,0,0,0,0};
    #pragma unroll
    for (int u = 0; u < 8; u++){
      u64 mm = mk[u];
      while (mm){
        int l = __builtin_ctzll(mm); mm &= mm - 1;
        const float* p = zA + (u * 64 + l) * 9;
        #pragma unroll
        for (int e = 0; e < 8; e++) a[e] += p[e];
      }
    }
    #pragma unroll
    for (int e = 0; e < 8; e++){ zB[t * 9 + e] = a[e]; aw1[e] = a[e]; }
  }
  __syncthreads();
  // w2 = A . w1 (reads zB; writes zA — safe: zA reads all completed pre-barrier)
  {
    float a[8] = {0,0,0,0,0,0,0,0};
    #pragma unroll
    for (int u = 0; u < 8; u++){
      u64 mm = mk[u];
      while (mm){
        int l = __builtin_ctzll(mm); mm &= mm - 1;
        const float* p = zB + (u * 64 + l) * 9;
        #pragma unroll
        for (int e = 0; e < 8; e++) a[e] += p[e];
      }
    }
    #pragma unroll
    for (int e = 0; e < 8; e++){ zA[t * 9 + e] = a[e]; aw2[e] = a[e]; }
  }
  // stage weights (512 threads, 448 elems)
  if (t < FIN * HID) Wl[t] = w1[t];
  if (t < HID){ Wl[448 + t] = pvec[t]; Wl[512 + t] = b1[t]; }
  __syncthreads();
  // w3 + finalize for OWN rows only
  if (own){
    #pragma unroll
    for (int e = 0; e < 8; e++) aw3[e] = 0.f;
    #pragma unroll
    for (int u = 0; u < 8; u++){
      u64 mm = mk[u];
      while (mm){
        int l = __builtin_ctzll(mm); mm &= mm - 1;
        const float* p = zA + (u * 64 + l) * 9;
        #pragma unroll
        for (int e = 0; e < 8; e++) aw3[e] += p[e];
      }
    }
    const int row = g * NDIM + t;
    const float s2v = dd * (c0 * dd + c1 * aw1[0] + c2 * aw2[0] + c3 * aw3[0]);
    float yin[FIN];
    #pragma unroll
    for (int f = 0; f < FIN; f++){
      float zv = dd * xr[f];
      float y = c0 * zv;
      y += c1 * aw1[f + 1];
      y += c2 * aw2[f + 1];
      y += c3 * aw3[f + 1];
      yin[f] = dd * y;
    }
    float hv[HID];
    float s1 = 0.f;
    #pragma unroll
    for (int o = 0; o < HID; o++){
      float zz = Wl[512 + o];
      #pragma unroll
      for (int f = 0; f < FIN; f++) zz = fmaf(yin[f], Wl[f * HID + o], zz);
      hv[o] = fmaxf(zz, 0.f);
      s1 = fmaf(hv[o], Wl[448 + o], s1);
    }
    score[row] = tanhf(beta[0] * s1 + beta[1] * s2v);
    float* hr = hbuf + (size_t)row * HID;
    #pragma unroll
    for (int o = 0; o < HID; o++) hr[o] = hv[o];
  }
}

// ---- top-k rank selection + xp gather -------------------------------------
__global__ __launch_bounds__(512) void topk_kernel(const float* __restrict__ score,
                                                   const float* __restrict__ hbuf,
                                                   int* __restrict__ idxOut,
                                                   float* __restrict__ xp)
{
  const int g = blockIdx.x, t = threadIdx.x;        // 512
  __shared__ float sv[NDIM];
  sv[t] = score[g * NDIM + t];
  __syncthreads();
  const float v = sv[t];
  int rank = 0;
  #pragma unroll 8
  for (int j = 0; j < NDIM; j++){
    float u_ = sv[j];
    rank += (u_ > v || (u_ == v && j < t)) ? 1 : 0;
  }
  if (rank < KPOOL){
    idxOut[g * KPOOL + rank] = t;
    const float* hr = hbuf + ((size_t)g * NDIM + t) * HID;
    float* xr = xp + ((size_t)g * KPOOL + rank) * HID;
    #pragma unroll
    for (int o = 0; o < HID; o++) xr[o] = hr[o] * v;
  }
}

// ---- pooled adjacency (fused A2p): Apool = Mn[idx,idx] + I, di ------------
__global__ __launch_bounds__(512) void pool_kernel(
    const u64* __restrict__ maskT, const int* __restrict__ idx,
    const float* __restrict__ dvec, const float* __restrict__ panw,
    float* __restrict__ Apool, float* __restrict__ di)
{
  const int b = blockIdx.x;
  const int g = b >> 3, rowgrp = b & 7;
  const int tid = threadIdx.x, w = tid >> 6, lane = tid & 63;
  __shared__ u64 mt[8][NDIM];                    // 32 KB
  __shared__ unsigned char arow[16][NDIM];       // 8 KB
  __shared__ int idxs[KPOOL];
  __shared__ float dp[KPOOL];
  {
    const uint4* s4 = (const uint4*)(maskT + (size_t)g * 8 * NDIM);
    uint4* d4 = (uint4*)&mt[0][0];
    #pragma unroll
    for (int s = 0; s < 4; s++) d4[tid + 512 * s] = s4[tid + 512 * s];
  }
  if (tid < KPOOL){
    int ia = idx[g * KPOOL + tid];
    idxs[tid] = ia;
    dp[tid] = dvec[g * NDIM + ia];
  }
  __syncthreads();
  // compute the 16 pooled A2 rows in-block (register-tiled popcounts)
  #pragma unroll
  for (int e = 0; e < 2; e++){
    const int j = w * 2 + e;
    const int ir = idxs[rowgrp * 16 + j];
    u64 rm[8];
    #pragma unroll
    for (int u = 0; u < 8; u++) rm[u] = mt[u][ir];   // wave-uniform broadcast
    #pragma unroll
    for (int q = 0; q < 8; q++){
      int c = 0;
      #pragma unroll
      for (int u = 0; u < 8; u++)
        c += (int)__popcll(mt[u][q * 64 + lane] & rm[u]);
      arow[j][q * 64 + lane] = (unsigned char)c;
    }
  }
  const int c0i = lane * 2, c1i = lane * 2 + 1;
  const int ic0 = idxs[c0i], ic1 = idxs[c1i];
  u64 cm0[8], cm1[8];
  #pragma unroll
  for (int u = 0; u < 8; u++){
    cm0[u] = mt[u][ic0];
    cm1[u] = mt[u][ic1];
  }
  __syncthreads();
  const float w0 = panw[0], ww1 = panw[1], ww2 = panw[2], ww3 = panw[3];
  const float cc0 = w0, cc1 = cc0 * ww1, cc2 = cc1 * ww2, cc3 = cc2 * ww3;
  const float dc0 = dp[c0i], dc1 = dp[c1i];
  #pragma unroll
  for (int e = 0; e < 2; e++){
    const int j = w * 2 + e;
    const int r = rowgrp * 16 + j;
    const int ir = idxs[r];
    const float dpr = dp[r];
    const unsigned char* aj = arow[j];
    float a30 = 0.f, a31 = 0.f;
    #pragma unroll
    for (int u = 0; u < 8; u++){
      u64 m0 = cm0[u];
      while (m0){ int l = __builtin_ctzll(m0); m0 &= m0 - 1; a30 += (float)aj[u * 64 + l]; }
      u64 m1 = cm1[u];
      while (m1){ int l = __builtin_ctzll(m1); m1 &= m1 - 1; a31 += (float)aj[u * 64 + l]; }
    }
    float ab0 = (float)((cm0[ir >> 6] >> (ir & 63)) & 1ull);
    float ab1 = (float)((cm1[ir >> 6] >> (ir & 63)) & 1ull);
    float m0 = fmaf(cc3, a30, fmaf(cc2, (float)aj[ic0], cc1 * ab0));
    float m1 = fmaf(cc3, a31, fmaf(cc2, (float)aj[ic1], cc1 * ab1));
    if (r == c0i) m0 += cc0;
    if (r == c1i) m1 += cc0;
    float v0 = m0 * dpr * dc0;
    float v1 = m1 * dpr * dc1;
    if (r == c0i) v0 += 1.0f;
    if (r == c1i) v1 += 1.0f;
    float2 vv = make_float2(v0, v1);
    *(float2*)&Apool[((size_t)g * KPOOL + r) * KPOOL + c0i] = vv;
    float s = wred64(v0 + v1);
    if (lane == 0) di[g * KPOOL + r] = s > 0.f ? rsqrtf(s) : 0.f;
  }
}

// ---------------- pooled GCN: h2 = relu((An xp) W + b) ---------------------
__global__ __launch_bounds__(256) void gcn_kernel(
    const float* __restrict__ Apool, const float* __restrict__ di,
    const float* __restrict__ xp, const float* __restrict__ gw,
    const float* __restrict__ gb, float* __restrict__ h2)
{
  const int wid = threadIdx.x >> 6, lane = threadIdx.x & 63;
  const int row = blockIdx.x * 4 + wid;
  const int g = row >> 7, r = row & 127;
  const float dir = di[g * KPOOL + r];
  float acc = 0.f;
  for (int b = 0; b < KPOOL; b++){
    float an = Apool[(size_t)row * KPOOL + b] * dir * di[g * KPOOL + b];
    acc = fmaf(an, xp[((size_t)g * KPOOL + b) * HID + lane], acc);
  }
  __shared__ float ts[4][HID];
  ts[wid][lane] = acc;
  __syncthreads();
  float z = gb[lane];
  for (int f = 0; f < HID; f++) z = fmaf(ts[wid][f], gw[f * HID + lane], z);
  h2[(size_t)row * HID + lane] = fmaxf(z, 0.f);
}

// ---------------- head: pooled sum + linear + log_softmax ------------------
__global__ void head_kernel(const float* __restrict__ h2,
                            const float* __restrict__ lw,
                            const float* __restrict__ lb,
                            float* __restrict__ out)
{
  const int g = blockIdx.x;
  const int lane = threadIdx.x;
  float p = 0.f;
  for (int k = 0; k < KPOOL; k++) p += h2[((size_t)g * KPOOL + k) * HID + lane];
  float z0 = p * lw[lane * CLS + 0];
  float z1 = p * lw[lane * CLS + 1];
  z0 = wred64(z0);
  z1 = wred64(z1);
  if (lane == 0){
    float l0 = z0 + lb[0], l1 = z1 + lb[1];
    float m = fmaxf(l0, l1);
    float lse = m + logf(expf(l0 - m) + expf(l1 - m));
    out[g * CLS + 0] = l0 - lse;
    out[g * CLS + 1] = l1 - lse;
  }
}

extern "C" void kernel_launch(void* const* d_in, const int* in_sizes, int n_in,
                              void* d_out, int out_size, void* d_ws, size_t ws_size,
                              hipStream_t stream)
{
  const float* x    = (const float*)d_in[0];
  const float* adj  = (const float*)d_in[1];
  const float* panw = (const float*)d_in[2];
  const float* w1   = (const float*)d_in[3];
  const float* b1   = (const float*)d_in[4];
  const float* pvec = (const float*)d_in[5];
  const float* beta = (const float*)d_in[6];
  const float* gw   = (const float*)d_in[7];
  const float* gbv  = (const float*)d_in[8];
  const float* lw   = (const float*)d_in[9];
  const float* lb   = (const float*)d_in[10];
  float* out = (float*)d_out;

  char* ws = (char*)d_ws;
  const size_t NR = (size_t)G * NDIM;            // 32768 rows
  u64* maskT = (u64*)ws;                         // 2 MB
  char* p = ws + (1 << 21);
  float* dvec  = (float*)p;  p += NR * 4;
  float* score = (float*)p;  p += NR * 4;
  float* hbuf  = (float*)p;  p += NR * HID * 4;  // 8 MB
  int*   idx   = (int*)p;    p += (size_t)G * KPOOL * 4;
  float* xp    = (float*)p;  p += (size_t)G * KPOOL * HID * 4;
  float* Apool = (float*)p;  p += (size_t)G * KPOOL * KPOOL * 4;
  float* di    = (float*)p;  p += (size_t)G * KPOOL * 4;
  float* h2    = (float*)p;

  mask_kernel<<<G * NDIM / 4, 256, 0, stream>>>(adj, maskT);
  mega_kernel<<<256, 512, 0, stream>>>(maskT, x, panw, w1, b1, pvec, beta,
                                       dvec, score, hbuf);
  topk_kernel<<<G, 512, 0, stream>>>(score, hbuf, idx, xp);
  pool_kernel<<<G * 8, 512, 0, stream>>>(maskT, idx, dvec, panw, Apool, di);
  gcn_kernel<<<G * KPOOL / 4, 256, 0, stream>>>(Apool, di, xp, gw, gbv, h2);
  head_kernel<<<G, 64, 0, stream>>>(h2, lw, lb, out);
}

// Round 20
// 133.155 us; speedup vs baseline: 2.6277x; 1.1848x over previous
//
#include <hip/hip_runtime.h>
#include <math.h>

#define G 64
#define NDIM 512
#define FIN 7
#define HID 64
#define CLS 2
#define KPOOL 128

typedef unsigned long long u64;

__device__ __forceinline__ float wred64(float v){
  #pragma unroll
  for (int o = 32; o > 0; o >>= 1) v += __shfl_xor(v, o, 64);
  return v;
}

// ---- build transposed bitmasks: maskT[g][u][i] bit l = adj[g][i][u*64+l] ---
__global__ __launch_bounds__(256) void mask_kernel(const float* __restrict__ adj,
                                                   u64* __restrict__ maskT){
  const int wid = threadIdx.x >> 6, lane = threadIdx.x & 63;
  const int row = blockIdx.x * 4 + wid;          // [0, G*NDIM)
  const int g = row >> 9, i = row & 511;
  const float* ar = adj + (size_t)row * NDIM;
  u64 b[8];
  #pragma unroll
  for (int u = 0; u < 8; u++)
    b[u] = __ballot(ar[u * 64 + lane] != 0.0f);
  if (lane == 0){
    u64* mt = maskT + (size_t)g * 8 * NDIM + i;
    #pragma unroll
    for (int u = 0; u < 8; u++) mt[(size_t)u * NDIM] = b[u];
  }
}

// ---- mega v3: B=4 blocks/graph, 512 threads, 1 row/thread (r19 proven) ----
__global__ __launch_bounds__(512) void mega_kernel(
    const u64* __restrict__ maskT, const float* __restrict__ x,
    const float* __restrict__ panw, const float* __restrict__ w1,
    const float* __restrict__ b1, const float* __restrict__ pvec,
    const float* __restrict__ beta,
    float* __restrict__ dvec, float* __restrict__ score,
    float* __restrict__ hbuf)
{
  __shared__ float deg_s[NDIM];                    // 2 KB
  __shared__ float d2_s[NDIM];                     // 2 KB
  __shared__ __align__(16) float zA[NDIM * 9];     // 18 KB
  __shared__ __align__(16) float zB[NDIM * 9];     // 18 KB
  __shared__ float Wl[576];                        // 2.3 KB

  const int bid = blockIdx.x;                      // [0,256)
  const int g = (bid & 7) + 8 * ((bid >> 3) & 7);  // graph -> XCD bid%8
  const int chunk = bid >> 6;                      // [0,4): own rows [128c,+128)
  const int t = threadIdx.x;                       // row [0,512)

  u64 mk[8];
  #pragma unroll
  for (int u = 0; u < 8; u++)
    mk[u] = maskT[(size_t)g * 8 * NDIM + (size_t)u * NDIM + t];
  float xr[FIN];
  {
    const float* px = x + ((size_t)g * NDIM + t) * FIN;
    #pragma unroll
    for (int f = 0; f < FIN; f++) xr[f] = px[f];
  }
  const float w0 = panw[0], ww1 = panw[1], ww2 = panw[2], ww3 = panw[3];
  const float c0 = w0, c1 = c0 * ww1, c2 = c1 * ww2, c3 = c2 * ww3;
  const bool own = (t >> 7) == chunk;

  float dg = 0.f;
  #pragma unroll
  for (int u = 0; u < 8; u++) dg += (float)__popcll(mk[u]);
  deg_s[t] = dg;
  __syncthreads();
  float d2 = 0.f;
  #pragma unroll
  for (int u = 0; u < 8; u++){
    u64 mm = mk[u];
    while (mm){ int l = __builtin_ctzll(mm); mm &= mm - 1; d2 += deg_s[u * 64 + l]; }
  }
  d2_s[t] = d2;
  __syncthreads();
  float d3 = 0.f;
  #pragma unroll
  for (int u = 0; u < 8; u++){
    u64 mm = mk[u];
    while (mm){ int l = __builtin_ctzll(mm); mm &= mm - 1; d3 += d2_s[u * 64 + l]; }
  }
  const float dd = rsqrtf(fmaxf(c0 + c1 * dg + c2 * d2 + c3 * d3, 1.0f));
  if (own) dvec[g * NDIM + t] = dd;
  zA[t * 9 + 0] = dd;
  #pragma unroll
  for (int f = 0; f < FIN; f++) zA[t * 9 + 1 + f] = dd * xr[f];
  __syncthreads();
  float aw1[8], aw2[8], aw3[8];
  {
    float a[8] = {0,0,0,0,0,0,0,0};
    #pragma unroll
    for (int u = 0; u < 8; u++){
      u64 mm = mk[u];
      while (mm){
        int l = __builtin_ctzll(mm); mm &= mm - 1;
        const float* p = zA + (u * 64 + l) * 9;
        #pragma unroll
        for (int e = 0; e < 8; e++) a[e] += p[e];
      }
    }
    #pragma unroll
    for (int e = 0; e < 8; e++){ zB[t * 9 + e] = a[e]; aw1[e] = a[e]; }
  }
  __syncthreads();
  {
    float a[8] = {0,0,0,0,0,0,0,0};
    #pragma unroll
    for (int u = 0; u < 8; u++){
      u64 mm = mk[u];
      while (mm){
        int l = __builtin_ctzll(mm); mm &= mm - 1;
        const float* p = zB + (u * 64 + l) * 9;
        #pragma unroll
        for (int e = 0; e < 8; e++) a[e] += p[e];
      }
    }
    #pragma unroll
    for (int e = 0; e < 8; e++){ zA[t * 9 + e] = a[e]; aw2[e] = a[e]; }
  }
  if (t < FIN * HID) Wl[t] = w1[t];
  if (t < HID){ Wl[448 + t] = pvec[t]; Wl[512 + t] = b1[t]; }
  __syncthreads();
  if (own){
    #pragma unroll
    for (int e = 0; e < 8; e++) aw3[e] = 0.f;
    #pragma unroll
    for (int u = 0; u < 8; u++){
      u64 mm = mk[u];
      while (mm){
        int l = __builtin_ctzll(mm); mm &= mm - 1;
        const float* p = zA + (u * 64 + l) * 9;
        #pragma unroll
        for (int e = 0; e < 8; e++) aw3[e] += p[e];
      }
    }
    const int row = g * NDIM + t;
    const float s2v = dd * (c0 * dd + c1 * aw1[0] + c2 * aw2[0] + c3 * aw3[0]);
    float yin[FIN];
    #pragma unroll
    for (int f = 0; f < FIN; f++){
      float zv = dd * xr[f];
      float y = c0 * zv;
      y += c1 * aw1[f + 1];
      y += c2 * aw2[f + 1];
      y += c3 * aw3[f + 1];
      yin[f] = dd * y;
    }
    float hv[HID];
    float s1 = 0.f;
    #pragma unroll
    for (int o = 0; o < HID; o++){
      float zz = Wl[512 + o];
      #pragma unroll
      for (int f = 0; f < FIN; f++) zz = fmaf(yin[f], Wl[f * HID + o], zz);
      hv[o] = fmaxf(zz, 0.f);
      s1 = fmaf(hv[o], Wl[448 + o], s1);
    }
    score[row] = tanhf(beta[0] * s1 + beta[1] * s2v);
    float* hr = hbuf + (size_t)row * HID;
    #pragma unroll
    for (int o = 0; o < HID; o++) hr[o] = hv[o];
  }
}

// ---- top-k rank selection + xp gather -------------------------------------
__global__ __launch_bounds__(512) void topk_kernel(const float* __restrict__ score,
                                                   const float* __restrict__ hbuf,
                                                   int* __restrict__ idxOut,
                                                   float* __restrict__ xp)
{
  const int g = blockIdx.x, t = threadIdx.x;        // 512
  __shared__ float sv[NDIM];
  sv[t] = score[g * NDIM + t];
  __syncthreads();
  const float v = sv[t];
  int rank = 0;
  #pragma unroll 8
  for (int j = 0; j < NDIM; j++){
    float u_ = sv[j];
    rank += (u_ > v || (u_ == v && j < t)) ? 1 : 0;
  }
  if (rank < KPOOL){
    idxOut[g * KPOOL + rank] = t;
    const float* hr = hbuf + ((size_t)g * NDIM + t) * HID;
    float* xr = xp + ((size_t)g * KPOOL + rank) * HID;
    #pragma unroll
    for (int o = 0; o < HID; o++) xr[o] = hr[o] * v;
  }
}

// ---- pool v3: merged-row A2p (half mt reads) + transposed pair-packed
//      arowT (one u16 read serves both rows; int accumulation, exact).
//      arowT[k][w] = A2[ir_j0][k] | A2[ir_j1][k]<<8, stride 9 u16 (18B).
__global__ __launch_bounds__(512) void pool_kernel(
    const u64* __restrict__ maskT, const int* __restrict__ idx,
    const float* __restrict__ dvec, const float* __restrict__ panw,
    float* __restrict__ Apool, float* __restrict__ di)
{
  const int b = blockIdx.x;
  const int g = b >> 3, rowgrp = b & 7;
  const int tid = threadIdx.x, w = tid >> 6, lane = tid & 63;
  __shared__ u64 mt[8][NDIM];                    // 32 KB
  __shared__ ushort arowT[NDIM][9];              // 9 KB (use col [w])
  __shared__ int idxs[KPOOL];
  __shared__ float dp[KPOOL];
  {
    const uint4* s4 = (const uint4*)(maskT + (size_t)g * 8 * NDIM);
    uint4* d4 = (uint4*)&mt[0][0];
    #pragma unroll
    for (int s = 0; s < 4; s++) d4[tid + 512 * s] = s4[tid + 512 * s];
  }
  if (tid < KPOOL){
    int ia = idx[g * KPOOL + tid];
    idxs[tid] = ia;
    dp[tid] = dvec[g * NDIM + ia];
  }
  __syncthreads();
  // this wave's two pooled rows
  const int ir0 = idxs[rowgrp * 16 + w * 2];
  const int ir1 = idxs[rowgrp * 16 + w * 2 + 1];
  u64 rm0[8], rm1[8];
  #pragma unroll
  for (int u = 0; u < 8; u++){ rm0[u] = mt[u][ir0]; rm1[u] = mt[u][ir1]; }
  // A2p both rows in one pass (mt read once per (q,u))
  #pragma unroll
  for (int q = 0; q < 8; q++){
    const int k = q * 64 + lane;
    int p0 = 0, p1 = 0;
    #pragma unroll
    for (int u = 0; u < 8; u++){
      u64 cm = mt[u][k];
      p0 += (int)__popcll(cm & rm0[u]);
      p1 += (int)__popcll(cm & rm1[u]);
    }
    arowT[k][w] = (ushort)(p0 | (p1 << 8));
  }
  // column masks for this lane's two pooled columns
  const int c0i = lane * 2, c1i = lane * 2 + 1;
  const int ic0 = idxs[c0i], ic1 = idxs[c1i];
  u64 cm0[8], cm1[8];
  #pragma unroll
  for (int u = 0; u < 8; u++){ cm0[u] = mt[u][ic0]; cm1[u] = mt[u][ic1]; }
  __syncthreads();
  // A3 walks: col c0i then c1i; each u16 read covers both rows (int, exact)
  int a300 = 0, a310 = 0, a301 = 0, a311 = 0;   // a3[row e][col 0/1]
  #pragma unroll
  for (int u = 0; u < 8; u++){
    u64 m0 = cm0[u];
    while (m0){
      int l = __builtin_ctzll(m0); m0 &= m0 - 1;
      ushort v = arowT[u * 64 + l][w];
      a300 += v & 0xFF; a310 += v >> 8;
    }
    u64 m1 = cm1[u];
    while (m1){
      int l = __builtin_ctzll(m1); m1 &= m1 - 1;
      ushort v = arowT[u * 64 + l][w];
      a301 += v & 0xFF; a311 += v >> 8;
    }
  }
  const ushort o0 = arowT[ic0][w];               // a2own: rows j0,j1 at col ic0
  const ushort o1 = arowT[ic1][w];               // rows j0,j1 at col ic1
  const float w0 = panw[0], ww1 = panw[1], ww2 = panw[2], ww3 = panw[3];
  const float cc0 = w0, cc1 = cc0 * ww1, cc2 = cc1 * ww2, cc3 = cc2 * ww3;
  const float dc0 = dp[c0i], dc1 = dp[c1i];
  float* Apg = Apool + (size_t)g * KPOOL * KPOOL;
  #pragma unroll
  for (int e = 0; e < 2; e++){
    const int r = rowgrp * 16 + w * 2 + e;
    const int ir = e ? ir1 : ir0;
    const float dpr = dp[r];
    const float a3c0 = (float)(e ? a310 : a300);
    const float a3c1 = (float)(e ? a311 : a301);
    const float a2c0 = (float)(e ? (o0 >> 8) : (o0 & 0xFF));
    const float a2c1 = (float)(e ? (o1 >> 8) : (o1 & 0xFF));
    float ab0 = (float)((cm0[ir >> 6] >> (ir & 63)) & 1ull);
    float ab1 = (float)((cm1[ir >> 6] >> (ir & 63)) & 1ull);
    float m0 = fmaf(cc3, a3c0, fmaf(cc2, a2c0, cc1 * ab0));
    float m1 = fmaf(cc3, a3c1, fmaf(cc2, a2c1, cc1 * ab1));
    if (r == c0i) m0 += cc0;
    if (r == c1i) m1 += cc0;
    float v0 = m0 * dpr * dc0;
    float v1 = m1 * dpr * dc1;
    if (r == c0i) v0 += 1.0f;
    if (r == c1i) v1 += 1.0f;
    *(float2*)&Apg[(size_t)r * KPOOL + c0i] = make_float2(v0, v1);
    float s = wred64(v0 + v1);
    if (lane == 0) di[g * KPOOL + r] = s > 0.f ? rsqrtf(s) : 0.f;
  }
}

// ---------------- pooled GCN: h2 = relu((An xp) W + b) ---------------------
__global__ __launch_bounds__(256) void gcn_kernel(
    const float* __restrict__ Apool, const float* __restrict__ di,
    const float* __restrict__ xp, const float* __restrict__ gw,
    const float* __restrict__ gb, float* __restrict__ h2)
{
  const int wid = threadIdx.x >> 6, lane = threadIdx.x & 63;
  const int row = blockIdx.x * 4 + wid;
  const int g = row >> 7, r = row & 127;
  const float dir = di[g * KPOOL + r];
  float acc = 0.f;
  for (int b = 0; b < KPOOL; b++){
    float an = Apool[(size_t)row * KPOOL + b] * dir * di[g * KPOOL + b];
    acc = fmaf(an, xp[((size_t)g * KPOOL + b) * HID + lane], acc);
  }
  __shared__ float ts[4][HID];
  ts[wid][lane] = acc;
  __syncthreads();
  float z = gb[lane];
  for (int f = 0; f < HID; f++) z = fmaf(ts[wid][f], gw[f * HID + lane], z);
  h2[(size_t)row * HID + lane] = fmaxf(z, 0.f);
}

// ---------------- head: pooled sum + linear + log_softmax ------------------
__global__ void head_kernel(const float* __restrict__ h2,
                            const float* __restrict__ lw,
                            const float* __restrict__ lb,
                            float* __restrict__ out)
{
  const int g = blockIdx.x;
  const int lane = threadIdx.x;
  float p = 0.f;
  for (int k = 0; k < KPOOL; k++) p += h2[((size_t)g * KPOOL + k) * HID + lane];
  float z0 = p * lw[lane * CLS + 0];
  float z1 = p * lw[lane * CLS + 1];
  z0 = wred64(z0);
  z1 = wred64(z1);
  if (lane == 0){
    float l0 = z0 + lb[0], l1 = z1 + lb[1];
    float m = fmaxf(l0, l1);
    float lse = m + logf(expf(l0 - m) + expf(l1 - m));
    out[g * CLS + 0] = l0 - lse;
    out[g * CLS + 1] = l1 - lse;
  }
}

extern "C" void kernel_launch(void* const* d_in, const int* in_sizes, int n_in,
                              void* d_out, int out_size, void* d_ws, size_t ws_size,
                              hipStream_t stream)
{
  const float* x    = (const float*)d_in[0];
  const float* adj  = (const float*)d_in[1];
  const float* panw = (const float*)d_in[2];
  const float* w1   = (const float*)d_in[3];
  const float* b1   = (const float*)d_in[4];
  const float* pvec = (const float*)d_in[5];
  const float* beta = (const float*)d_in[6];
  const float* gw   = (const float*)d_in[7];
  const float* gbv  = (const float*)d_in[8];
  const float* lw   = (const float*)d_in[9];
  const float* lb   = (const float*)d_in[10];
  float* out = (float*)d_out;

  char* ws = (char*)d_ws;
  const size_t NR = (size_t)G * NDIM;            // 32768 rows
  u64* maskT = (u64*)ws;                         // 2 MB
  char* p = ws + (1 << 21);
  float* dvec  = (float*)p;  p += NR * 4;
  float* score = (float*)p;  p += NR * 4;
  float* hbuf  = (float*)p;  p += NR * HID * 4;  // 8 MB
  int*   idx   = (int*)p;    p += (size_t)G * KPOOL * 4;
  float* xp    = (float*)p;  p += (size_t)G * KPOOL * HID * 4;
  float* Apool = (float*)p;  p += (size_t)G * KPOOL * KPOOL * 4;
  float* di    = (float*)p;  p += (size_t)G * KPOOL * 4;
  float* h2    = (float*)p;

  mask_kernel<<<G * NDIM / 4, 256, 0, stream>>>(adj, maskT);
  mega_kernel<<<256, 512, 0, stream>>>(maskT, x, panw, w1, b1, pvec, beta,
                                       dvec, score, hbuf);
  topk_kernel<<<G, 512, 0, stream>>>(score, hbuf, idx, xp);
  pool_kernel<<<G * 8, 512, 0, stream>>>(maskT, idx, dvec, panw, Apool, di);
  gcn_kernel<<<G * KPOOL / 4, 256, 0, stream>>>(Apool, di, xp, gw, gbv, h2);
  head_kernel<<<G, 64, 0, stream>>>(h2, lw, lb, out);
}

// Round 21
// 128.000 us; speedup vs baseline: 2.7335x; 1.0403x over previous
//
#include <hip/hip_runtime.h>
#include <math.h>

#define G 64
#define NDIM 512
#define FIN 7
#define HID 64
#define CLS 2
#define KPOOL 128

typedef unsigned long long u64;

__device__ __forceinline__ float wred64(float v){
  #pragma unroll
  for (int o = 32; o > 0; o >>= 1) v += __shfl_xor(v, o, 64);
  return v;
}

// ---- build transposed bitmasks: maskT[g][u][i] bit l = adj[g][i][u*64+l] ---
__global__ __launch_bounds__(256) void mask_kernel(const float* __restrict__ adj,
                                                   u64* __restrict__ maskT){
  const int wid = threadIdx.x >> 6, lane = threadIdx.x & 63;
  const int row = blockIdx.x * 4 + wid;          // [0, G*NDIM)
  const int g = row >> 9, i = row & 511;
  const float* ar = adj + (size_t)row * NDIM;
  u64 b[8];
  #pragma unroll
  for (int u = 0; u < 8; u++)
    b[u] = __ballot(ar[u * 64 + lane] != 0.0f);
  if (lane == 0){
    u64* mt = maskT + (size_t)g * 8 * NDIM + i;
    #pragma unroll
    for (int u = 0; u < 8; u++) mt[(size_t)u * NDIM] = b[u];
  }
}

// ---- mega v4: B=4 blocks/graph, 512 threads, 1 row/thread.
//      z/w tables: STRIDE-12 (48B) rows — 16B-aligned every row => each
//      neighbor read is 2x ds_read_b128 (was 8x b32; m134: ~24 vs ~46 cyc).
//      Row-start banks (12k)%32 cycle 8 positions — ~2-way like stride-9.
//      LDS 54.3 KB (1 block/CU as before).
__global__ __launch_bounds__(512) void mega_kernel(
    const u64* __restrict__ maskT, const float* __restrict__ x,
    const float* __restrict__ panw, const float* __restrict__ w1,
    const float* __restrict__ b1, const float* __restrict__ pvec,
    const float* __restrict__ beta,
    float* __restrict__ dvec, float* __restrict__ score,
    float* __restrict__ hbuf)
{
  __shared__ float deg_s[NDIM];                    // 2 KB
  __shared__ float d2_s[NDIM];                     // 2 KB
  __shared__ __align__(16) float zA[NDIM * 12];    // 24 KB
  __shared__ __align__(16) float zB[NDIM * 12];    // 24 KB
  __shared__ float Wl[576];                        // 2.3 KB

  const int bid = blockIdx.x;                      // [0,256)
  const int g = (bid & 7) + 8 * ((bid >> 3) & 7);  // graph -> XCD bid%8
  const int chunk = bid >> 6;                      // [0,4): own rows [128c,+128)
  const int t = threadIdx.x;                       // row [0,512)

  u64 mk[8];
  #pragma unroll
  for (int u = 0; u < 8; u++)
    mk[u] = maskT[(size_t)g * 8 * NDIM + (size_t)u * NDIM + t];
  float xr[FIN];
  {
    const float* px = x + ((size_t)g * NDIM + t) * FIN;
    #pragma unroll
    for (int f = 0; f < FIN; f++) xr[f] = px[f];
  }
  const float w0 = panw[0], ww1 = panw[1], ww2 = panw[2], ww3 = panw[3];
  const float c0 = w0, c1 = c0 * ww1, c2 = c1 * ww2, c3 = c2 * ww3;
  const bool own = (t >> 7) == chunk;

  float dg = 0.f;
  #pragma unroll
  for (int u = 0; u < 8; u++) dg += (float)__popcll(mk[u]);
  deg_s[t] = dg;
  __syncthreads();
  float d2 = 0.f;
  #pragma unroll
  for (int u = 0; u < 8; u++){
    u64 mm = mk[u];
    while (mm){ int l = __builtin_ctzll(mm); mm &= mm - 1; d2 += deg_s[u * 64 + l]; }
  }
  d2_s[t] = d2;
  __syncthreads();
  float d3 = 0.f;
  #pragma unroll
  for (int u = 0; u < 8; u++){
    u64 mm = mk[u];
    while (mm){ int l = __builtin_ctzll(mm); mm &= mm - 1; d3 += d2_s[u * 64 + l]; }
  }
  const float dd = rsqrtf(fmaxf(c0 + c1 * dg + c2 * d2 + c3 * d3, 1.0f));
  if (own) dvec[g * NDIM + t] = dd;
  // z = [dd, dd*x] — two float4 stores (stride-12 rows, 16B-aligned)
  *(float4*)(zA + t * 12)     = make_float4(dd, dd * xr[0], dd * xr[1], dd * xr[2]);
  *(float4*)(zA + t * 12 + 4) = make_float4(dd * xr[3], dd * xr[4], dd * xr[5], dd * xr[6]);
  __syncthreads();
  float aw1[8], aw2[8], aw3[8];
  // w1 = A . z
  {
    float a[8] = {0,0,0,0,0,0,0,0};
    #pragma unroll
    for (int u = 0; u < 8; u++){
      u64 mm = mk[u];
      while (mm){
        int l = __builtin_ctzll(mm); mm &= mm - 1;
        const float4* p = (const float4*)(zA + (u * 64 + l) * 12);
        float4 v0 = p[0], v1 = p[1];
        a[0] += v0.x; a[1] += v0.y; a[2] += v0.z; a[3] += v0.w;
        a[4] += v1.x; a[5] += v1.y; a[6] += v1.z; a[7] += v1.w;
      }
    }
    *(float4*)(zB + t * 12)     = make_float4(a[0], a[1], a[2], a[3]);
    *(float4*)(zB + t * 12 + 4) = make_float4(a[4], a[5], a[6], a[7]);
    #pragma unroll
    for (int e = 0; e < 8; e++) aw1[e] = a[e];
  }
  __syncthreads();
  // w2 = A . w1 (reads zB; writes zA)
  {
    float a[8] = {0,0,0,0,0,0,0,0};
    #pragma unroll
    for (int u = 0; u < 8; u++){
      u64 mm = mk[u];
      while (mm){
        int l = __builtin_ctzll(mm); mm &= mm - 1;
        const float4* p = (const float4*)(zB + (u * 64 + l) * 12);
        float4 v0 = p[0], v1 = p[1];
        a[0] += v0.x; a[1] += v0.y; a[2] += v0.z; a[3] += v0.w;
        a[4] += v1.x; a[5] += v1.y; a[6] += v1.z; a[7] += v1.w;
      }
    }
    *(float4*)(zA + t * 12)     = make_float4(a[0], a[1], a[2], a[3]);
    *(float4*)(zA + t * 12 + 4) = make_float4(a[4], a[5], a[6], a[7]);
    #pragma unroll
    for (int e = 0; e < 8; e++) aw2[e] = a[e];
  }
  if (t < FIN * HID) Wl[t] = w1[t];
  if (t < HID){ Wl[448 + t] = pvec[t]; Wl[512 + t] = b1[t]; }
  __syncthreads();
  // w3 + finalize for OWN rows only
  if (own){
    #pragma unroll
    for (int e = 0; e < 8; e++) aw3[e] = 0.f;
    #pragma unroll
    for (int u = 0; u < 8; u++){
      u64 mm = mk[u];
      while (mm){
        int l = __builtin_ctzll(mm); mm &= mm - 1;
        const float4* p = (const float4*)(zA + (u * 64 + l) * 12);
        float4 v0 = p[0], v1 = p[1];
        aw3[0] += v0.x; aw3[1] += v0.y; aw3[2] += v0.z; aw3[3] += v0.w;
        aw3[4] += v1.x; aw3[5] += v1.y; aw3[6] += v1.z; aw3[7] += v1.w;
      }
    }
    const int row = g * NDIM + t;
    const float s2v = dd * (c0 * dd + c1 * aw1[0] + c2 * aw2[0] + c3 * aw3[0]);
    float yin[FIN];
    #pragma unroll
    for (int f = 0; f < FIN; f++){
      float zv = dd * xr[f];
      float y = c0 * zv;
      y += c1 * aw1[f + 1];
      y += c2 * aw2[f + 1];
      y += c3 * aw3[f + 1];
      yin[f] = dd * y;
    }
    float hv[HID];
    float s1 = 0.f;
    #pragma unroll
    for (int o = 0; o < HID; o++){
      float zz = Wl[512 + o];
      #pragma unroll
      for (int f = 0; f < FIN; f++) zz = fmaf(yin[f], Wl[f * HID + o], zz);
      hv[o] = fmaxf(zz, 0.f);
      s1 = fmaf(hv[o], Wl[448 + o], s1);
    }
    score[row] = tanhf(beta[0] * s1 + beta[1] * s2v);
    float* hr = hbuf + (size_t)row * HID;
    #pragma unroll
    for (int o = 0; o < HID; o++) hr[o] = hv[o];
  }
}

// ---- top-k rank selection + xp gather -------------------------------------
__global__ __launch_bounds__(512) void topk_kernel(const float* __restrict__ score,
                                                   const float* __restrict__ hbuf,
                                                   int* __restrict__ idxOut,
                                                   float* __restrict__ xp)
{
  const int g = blockIdx.x, t = threadIdx.x;        // 512
  __shared__ float sv[NDIM];
  sv[t] = score[g * NDIM + t];
  __syncthreads();
  const float v = sv[t];
  int rank = 0;
  #pragma unroll 8
  for (int j = 0; j < NDIM; j++){
    float u_ = sv[j];
    rank += (u_ > v || (u_ == v && j < t)) ? 1 : 0;
  }
  if (rank < KPOOL){
    idxOut[g * KPOOL + rank] = t;
    const float* hr = hbuf + ((size_t)g * NDIM + t) * HID;
    float* xr = xp + ((size_t)g * KPOOL + rank) * HID;
    #pragma unroll
    for (int o = 0; o < HID; o++) xr[o] = hr[o] * v;
  }
}

// ---- pool v3: merged-row A2p + transposed pair-packed arowT (r20 proven) --
__global__ __launch_bounds__(512) void pool_kernel(
    const u64* __restrict__ maskT, const int* __restrict__ idx,
    const float* __restrict__ dvec, const float* __restrict__ panw,
    float* __restrict__ Apool, float* __restrict__ di)
{
  const int b = blockIdx.x;
  const int g = b >> 3, rowgrp = b & 7;
  const int tid = threadIdx.x, w = tid >> 6, lane = tid & 63;
  __shared__ u64 mt[8][NDIM];                    // 32 KB
  __shared__ ushort arowT[NDIM][9];              // 9 KB (use col [w])
  __shared__ int idxs[KPOOL];
  __shared__ float dp[KPOOL];
  {
    const uint4* s4 = (const uint4*)(maskT + (size_t)g * 8 * NDIM);
    uint4* d4 = (uint4*)&mt[0][0];
    #pragma unroll
    for (int s = 0; s < 4; s++) d4[tid + 512 * s] = s4[tid + 512 * s];
  }
  if (tid < KPOOL){
    int ia = idx[g * KPOOL + tid];
    idxs[tid] = ia;
    dp[tid] = dvec[g * NDIM + ia];
  }
  __syncthreads();
  const int ir0 = idxs[rowgrp * 16 + w * 2];
  const int ir1 = idxs[rowgrp * 16 + w * 2 + 1];
  u64 rm0[8], rm1[8];
  #pragma unroll
  for (int u = 0; u < 8; u++){ rm0[u] = mt[u][ir0]; rm1[u] = mt[u][ir1]; }
  #pragma unroll
  for (int q = 0; q < 8; q++){
    const int k = q * 64 + lane;
    int p0 = 0, p1 = 0;
    #pragma unroll
    for (int u = 0; u < 8; u++){
      u64 cm = mt[u][k];
      p0 += (int)__popcll(cm & rm0[u]);
      p1 += (int)__popcll(cm & rm1[u]);
    }
    arowT[k][w] = (ushort)(p0 | (p1 << 8));
  }
  const int c0i = lane * 2, c1i = lane * 2 + 1;
  const int ic0 = idxs[c0i], ic1 = idxs[c1i];
  u64 cm0[8], cm1[8];
  #pragma unroll
  for (int u = 0; u < 8; u++){ cm0[u] = mt[u][ic0]; cm1[u] = mt[u][ic1]; }
  __syncthreads();
  int a300 = 0, a310 = 0, a301 = 0, a311 = 0;
  #pragma unroll
  for (int u = 0; u < 8; u++){
    u64 m0 = cm0[u];
    while (m0){
      int l = __builtin_ctzll(m0); m0 &= m0 - 1;
      ushort v = arowT[u * 64 + l][w];
      a300 += v & 0xFF; a310 += v >> 8;
    }
    u64 m1 = cm1[u];
    while (m1){
      int l = __builtin_ctzll(m1); m1 &= m1 - 1;
      ushort v = arowT[u * 64 + l][w];
      a301 += v & 0xFF; a311 += v >> 8;
    }
  }
  const ushort o0 = arowT[ic0][w];
  const ushort o1 = arowT[ic1][w];
  const float w0 = panw[0], ww1 = panw[1], ww2 = panw[2], ww3 = panw[3];
  const float cc0 = w0, cc1 = cc0 * ww1, cc2 = cc1 * ww2, cc3 = cc2 * ww3;
  const float dc0 = dp[c0i], dc1 = dp[c1i];
  float* Apg = Apool + (size_t)g * KPOOL * KPOOL;
  #pragma unroll
  for (int e = 0; e < 2; e++){
    const int r = rowgrp * 16 + w * 2 + e;
    const int ir = e ? ir1 : ir0;
    const float dpr = dp[r];
    const float a3c0 = (float)(e ? a310 : a300);
    const float a3c1 = (float)(e ? a311 : a301);
    const float a2c0 = (float)(e ? (o0 >> 8) : (o0 & 0xFF));
    const float a2c1 = (float)(e ? (o1 >> 8) : (o1 & 0xFF));
    float ab0 = (float)((cm0[ir >> 6] >> (ir & 63)) & 1ull);
    float ab1 = (float)((cm1[ir >> 6] >> (ir & 63)) & 1ull);
    float m0 = fmaf(cc3, a3c0, fmaf(cc2, a2c0, cc1 * ab0));
    float m1 = fmaf(cc3, a3c1, fmaf(cc2, a2c1, cc1 * ab1));
    if (r == c0i) m0 += cc0;
    if (r == c1i) m1 += cc0;
    float v0 = m0 * dpr * dc0;
    float v1 = m1 * dpr * dc1;
    if (r == c0i) v0 += 1.0f;
    if (r == c1i) v1 += 1.0f;
    *(float2*)&Apg[(size_t)r * KPOOL + c0i] = make_float2(v0, v1);
    float s = wred64(v0 + v1);
    if (lane == 0) di[g * KPOOL + r] = s > 0.f ? rsqrtf(s) : 0.f;
  }
}

// ---------------- pooled GCN: h2 = relu((An xp) W + b) ---------------------
__global__ __launch_bounds__(256) void gcn_kernel(
    const float* __restrict__ Apool, const float* __restrict__ di,
    const float* __restrict__ xp, const float* __restrict__ gw,
    const float* __restrict__ gb, float* __restrict__ h2)
{
  const int wid = threadIdx.x >> 6, lane = threadIdx.x & 63;
  const int row = blockIdx.x * 4 + wid;
  const int g = row >> 7, r = row & 127;
  const float dir = di[g * KPOOL + r];
  float acc = 0.f;
  for (int b = 0; b < KPOOL; b++){
    float an = Apool[(size_t)row * KPOOL + b] * dir * di[g * KPOOL + b];
    acc = fmaf(an, xp[((size_t)g * KPOOL + b) * HID + lane], acc);
  }
  __shared__ float ts[4][HID];
  ts[wid][lane] = acc;
  __syncthreads();
  float z = gb[lane];
  for (int f = 0; f < HID; f++) z = fmaf(ts[wid][f], gw[f * HID + lane], z);
  h2[(size_t)row * HID + lane] = fmaxf(z, 0.f);
}

// ---------------- head: pooled sum + linear + log_softmax ------------------
__global__ void head_kernel(const float* __restrict__ h2,
                            const float* __restrict__ lw,
                            const float* __restrict__ lb,
                            float* __restrict__ out)
{
  const int g = blockIdx.x;
  const int lane = threadIdx.x;
  float p = 0.f;
  for (int k = 0; k < KPOOL; k++) p += h2[((size_t)g * KPOOL + k) * HID + lane];
  float z0 = p * lw[lane * CLS + 0];
  float z1 = p * lw[lane * CLS + 1];
  z0 = wred64(z0);
  z1 = wred64(z1);
  if (lane == 0){
    float l0 = z0 + lb[0], l1 = z1 + lb[1];
    float m = fmaxf(l0, l1);
    float lse = m + logf(expf(l0 - m) + expf(l1 - m));
    out[g * CLS + 0] = l0 - lse;
    out[g * CLS + 1] = l1 - lse;
  }
}

extern "C" void kernel_launch(void* const* d_in, const int* in_sizes, int n_in,
                              void* d_out, int out_size, void* d_ws, size_t ws_size,
                              hipStream_t stream)
{
  const float* x    = (const float*)d_in[0];
  const float* adj  = (const float*)d_in[1];
  const float* panw = (const float*)d_in[2];
  const float* w1   = (const float*)d_in[3];
  const float* b1   = (const float*)d_in[4];
  const float* pvec = (const float*)d_in[5];
  const float* beta = (const float*)d_in[6];
  const float* gw   = (const float*)d_in[7];
  const float* gbv  = (const float*)d_in[8];
  const float* lw   = (const float*)d_in[9];
  const float* lb   = (const float*)d_in[10];
  float* out = (float*)d_out;

  char* ws = (char*)d_ws;
  const size_t NR = (size_t)G * NDIM;            // 32768 rows
  u64* maskT = (u64*)ws;                         // 2 MB
  char* p = ws + (1 << 21);
  float* dvec  = (float*)p;  p += NR * 4;
  float* score = (float*)p;  p += NR * 4;
  float* hbuf  = (float*)p;  p += NR * HID * 4;  // 8 MB
  int*   idx   = (int*)p;    p += (size_t)G * KPOOL * 4;
  float* xp    = (float*)p;  p += (size_t)G * KPOOL * HID * 4;
  float* Apool = (float*)p;  p += (size_t)G * KPOOL * KPOOL * 4;
  float* di    = (float*)p;  p += (size_t)G * KPOOL * 4;
  float* h2    = (float*)p;

  mask_kernel<<<G * NDIM / 4, 256, 0, stream>>>(adj, maskT);
  mega_kernel<<<256, 512, 0, stream>>>(maskT, x, panw, w1, b1, pvec, beta,
                                       dvec, score, hbuf);
  topk_kernel<<<G, 512, 0, stream>>>(score, hbuf, idx, xp);
  pool_kernel<<<G * 8, 512, 0, stream>>>(maskT, idx, dvec, panw, Apool, di);
  gcn_kernel<<<G * KPOOL / 4, 256, 0, stream>>>(Apool, di, xp, gw, gbv, h2);
  head_kernel<<<G, 64, 0, stream>>>(h2, lw, lb, out);
}